// Round 9
// baseline (161818.445 us; speedup 1.0000x reference)
//
#include <hip/hip_runtime.h>
#include <hip/hip_cooperative_groups.h>
#include <math.h>

namespace cg = cooperative_groups;

#define HD 1024
#define BB 50
#define SS 457
#define TT 32
#define VV 27

#define SSTR 68
#define WSTR 68

#define SIGM(v) (1.f / (1.f + expf(-(v))))

// ===========================================================================
// Persistent cooperative encoder: 256 WGs x 1024 threads, 458 phases.
// Round-9: L0+L1 FUSED single pass per phase; weights staged global->LDS via
// per-lane VECTOR loads (round-8's wave-uniform scalar loads were the 63 ms:
// s_load serialization + per-phase L2 miss of the 36 MB weight stream).
// Phase p: L0: h0[p] = GRU(x_p, h0[p-1]); L1: h1[p-1] = GRU(h0[p-1], h1[p-2])
// -> enc[p-1]. Both read h0r. One grid.sync per phase.
// WG owns 4 j-columns. wave wu (0..15) = k-f4 slot; lane = batch.
// Per thread/window: 2 ds_read_b128 (h0,h1) + 36 broadcast ds_read_b128
// (weights, conflict-free) + 144 FMAs. Double-buffered, prefetch-before-
// compute. 28 f32 accumulators; 4-slab deterministic k-reduction.
// ===========================================================================
struct EncArgs {
  const float *x, *Wih0, *Whh0, *bih0, *bhh0, *Wih1, *Whh1, *bih1, *bhh1;
  float *h0a, *h0b2, *h1a, *h1b2, *enc;
};

__device__ __forceinline__ float dot4f(float4 w, float4 h, float a) {
  a = fmaf(w.x, h.x, a);
  a = fmaf(w.y, h.y, a);
  a = fmaf(w.z, h.z, a);
  a = fmaf(w.w, h.w, a);
  return a;
}

__global__ __launch_bounds__(1024, 4) void enc_persistent(EncArgs A)
{
  __shared__ __align__(16) float Hs[2][2][64][SSTR]; // [buf][src][b][k] 69.6KB
  __shared__ __align__(16) float Wt[2][36][64];      // [buf][row][k]    18.4KB
  __shared__ float part[4][28][66];                  // k-slabs          29.6KB

  const int tid = threadIdx.x;
  const int wj0 = blockIdx.x * 4;                        // 4 j-cols, <=1020
  const int b   = tid & 63;                              // lane = batch
  const int wu  = __builtin_amdgcn_readfirstlane(tid >> 6); // wave 0..15
  const int sb  = tid >> 4;                              // h staging row
  const int sbc = sb < BB ? sb : BB - 1;
  const int sf4 = tid & 15;                              // k-f4 in window

  // weight staging role (tid < 576): 36 rows x 16 f4
  const int wr  = tid >> 4;            // 0..35 (valid when tid<576)
  const int wf4 = tid & 15;
  const int wmat = wr / 12;            // 0:Whh0 1:Wih1 2:Whh1
  const int wloc = wr - wmat * 12;
  const int wrow = (wloc >> 2) * 1024 + wj0 + (wloc & 3);   // <= 3071

  cg::grid_group grid = cg::this_grid();

  float* h0buf[2] = { A.h0a, A.h0b2 };
  float* h1buf[2] = { A.h1a, A.h1b2 };

  const float* wbase = A.Whh0;
  if (tid < 576) {
    const float* Wm = (wmat == 0) ? A.Whh0 : ((wmat == 1) ? A.Wih1 : A.Whh1);
    wbase = Wm + (size_t)wrow * 1024;
  }

  for (int p = 0; p <= 457; ++p) {
    const float* h0r = h0buf[(p + 1) & 1];
    float*       h0w = h0buf[p & 1];
    const float* h1r = h1buf[p & 1];
    float*       h1w = h1buf[(p + 1) & 1];

    // 28 accumulators (all statically indexed)
    float a0R[4], a0Z[4], a0N[4], a1R[4], a1Z[4], a1Ni[4], a1Nh[4];
#pragma unroll
    for (int jl = 0; jl < 4; ++jl) {
      a0R[jl] = 0.f; a0Z[jl] = 0.f; a0N[jl] = 0.f;
      a1R[jl] = 0.f; a1Z[jl] = 0.f; a1Ni[jl] = 0.f; a1Nh[jl] = 0.f;
    }

    // ---- prologue: stage window 0 into buf 0 ----
    {
      float4 h0g = *(const float4*)(h0r + (size_t)sbc * 1024 + (sf4 << 2));
      float4 h1g = *(const float4*)(h1r + (size_t)sbc * 1024 + (sf4 << 2));
      float4 wvv = make_float4(0.f, 0.f, 0.f, 0.f);
      if (tid < 576) wvv = *(const float4*)(wbase + (wf4 << 2));
      *(float4*)&Hs[0][0][sb][sf4 << 2] = h0g;
      *(float4*)&Hs[0][1][sb][sf4 << 2] = h1g;
      if (tid < 576) *(float4*)&Wt[0][wr][wf4 << 2] = wvv;
    }
    __syncthreads();

    for (int win = 0; win < 16; ++win) {
      const int buf = win & 1;
      // ---- prefetch next window (vector loads, latency hides under FMAs) --
      float4 h0g2 = make_float4(0.f, 0.f, 0.f, 0.f);
      float4 h1g2 = make_float4(0.f, 0.f, 0.f, 0.f);
      float4 wv2  = make_float4(0.f, 0.f, 0.f, 0.f);
      if (win < 15) {
        const int ko = (win + 1) << 6;
        h0g2 = *(const float4*)(h0r + (size_t)sbc * 1024 + ko + (sf4 << 2));
        h1g2 = *(const float4*)(h1r + (size_t)sbc * 1024 + ko + (sf4 << 2));
        if (tid < 576) wv2 = *(const float4*)(wbase + ko + (wf4 << 2));
      }

      // ---- compute current window ----
      const float4 hv0 = *(const float4*)&Hs[buf][0][b][wu << 2];
      const float4 hv1 = *(const float4*)&Hs[buf][1][b][wu << 2];
#pragma unroll
      for (int jl = 0; jl < 4; ++jl) {
        const int kc = wu << 2;
        const float4 wL0r = *(const float4*)&Wt[buf][jl][kc];
        const float4 wL0z = *(const float4*)&Wt[buf][4 + jl][kc];
        const float4 wL0n = *(const float4*)&Wt[buf][8 + jl][kc];
        const float4 wGiR = *(const float4*)&Wt[buf][12 + jl][kc];
        const float4 wGiZ = *(const float4*)&Wt[buf][16 + jl][kc];
        const float4 wGiN = *(const float4*)&Wt[buf][20 + jl][kc];
        const float4 wGhR = *(const float4*)&Wt[buf][24 + jl][kc];
        const float4 wGhZ = *(const float4*)&Wt[buf][28 + jl][kc];
        const float4 wGhN = *(const float4*)&Wt[buf][32 + jl][kc];
        a0R[jl]  = dot4f(wL0r, hv0, a0R[jl]);
        a0Z[jl]  = dot4f(wL0z, hv0, a0Z[jl]);
        a0N[jl]  = dot4f(wL0n, hv0, a0N[jl]);
        a1R[jl]  = dot4f(wGiR, hv0, a1R[jl]);   // gi part
        a1Z[jl]  = dot4f(wGiZ, hv0, a1Z[jl]);
        a1Ni[jl] = dot4f(wGiN, hv0, a1Ni[jl]);
        a1R[jl]  = dot4f(wGhR, hv1, a1R[jl]);   // gh part (r,z sum directly)
        a1Z[jl]  = dot4f(wGhZ, hv1, a1Z[jl]);
        a1Nh[jl] = dot4f(wGhN, hv1, a1Nh[jl]);
      }

      // ---- commit prefetch into other buffer ----
      if (win < 15) {
        const int nb = buf ^ 1;
        *(float4*)&Hs[nb][0][sb][sf4 << 2] = h0g2;
        *(float4*)&Hs[nb][1][sb][sf4 << 2] = h1g2;
        if (tid < 576) *(float4*)&Wt[nb][wr][wf4 << 2] = wv2;
      }
      __syncthreads();
    }

    // ---- deterministic k-slot reduction: 4 slabs, 3 add rounds ----
    if (wu < 4) {
#pragma unroll
      for (int jl = 0; jl < 4; ++jl) {
        part[wu][jl][b]      = a0R[jl];
        part[wu][4 + jl][b]  = a0Z[jl];
        part[wu][8 + jl][b]  = a0N[jl];
        part[wu][12 + jl][b] = a1R[jl];
        part[wu][16 + jl][b] = a1Z[jl];
        part[wu][20 + jl][b] = a1Ni[jl];
        part[wu][24 + jl][b] = a1Nh[jl];
      }
    }
    __syncthreads();
#pragma unroll
    for (int rnd = 1; rnd < 4; ++rnd) {
      if ((wu >> 2) == rnd) {
        const int sl = wu & 3;
#pragma unroll
        for (int jl = 0; jl < 4; ++jl) {
          part[sl][jl][b]      += a0R[jl];
          part[sl][4 + jl][b]  += a0Z[jl];
          part[sl][8 + jl][b]  += a0N[jl];
          part[sl][12 + jl][b] += a1R[jl];
          part[sl][16 + jl][b] += a1Z[jl];
          part[sl][20 + jl][b] += a1Ni[jl];
          part[sl][24 + jl][b] += a1Nh[jl];
        }
      }
      __syncthreads();
    }

    // ---- epilogues (tid < 200: jl 0..3 x b 0..49) ----
    if (tid < 200) {
      const int jl = tid / 50, bb = tid - jl * 50;
      const int j = wj0 + jl;
      auto sum4 = [&](int r) {
        return part[0][r][bb] + part[1][r][bb] + part[2][r][bb] + part[3][r][bb];
      };
      if (p < 457) {          // L0 gate: h0[p]
        const float dR  = sum4(jl);
        const float dZ  = sum4(4 + jl);
        const float dNh = sum4(8 + jl);
        const float x0 = A.x[bb * 914 + p];
        const float x1 = A.x[bb * 914 + 457 + p];
        const float pf = (float)p;
        const float* w3r = A.Wih0 + (size_t)j * 3;
        const float* w3z = A.Wih0 + (size_t)(1024 + j) * 3;
        const float* w3n = A.Wih0 + (size_t)(2048 + j) * 3;
        const float gir = w3r[0]*x0 + w3r[1]*x1 + w3r[2]*pf + A.bih0[j];
        const float giz = w3z[0]*x0 + w3z[1]*x1 + w3z[2]*pf + A.bih0[1024 + j];
        const float gin = w3n[0]*x0 + w3n[1]*x1 + w3n[2]*pf + A.bih0[2048 + j];
        const float rr = SIGM(gir + dR + A.bhh0[j]);
        const float zz = SIGM(giz + dZ + A.bhh0[1024 + j]);
        const float nn = tanhf(gin + rr * (dNh + A.bhh0[2048 + j]));
        const float hv0 = h0r[bb * 1024 + j];
        h0w[bb * 1024 + j] = (1.f - zz) * nn + zz * hv0;
      }
      if (p > 0) {            // L1 gate: h1[p-1] -> enc[p-1]
        const float dR  = sum4(12 + jl);
        const float dZ  = sum4(16 + jl);
        const float dNi = sum4(20 + jl);
        const float dNh = sum4(24 + jl);
        const float rr = SIGM(dR + A.bih1[j] + A.bhh1[j]);
        const float zz = SIGM(dZ + A.bih1[1024 + j] + A.bhh1[1024 + j]);
        const float nn = tanhf(dNi + A.bih1[2048 + j] + rr * (dNh + A.bhh1[2048 + j]));
        const float hv1 = h1r[bb * 1024 + j];
        const float h2 = (1.f - zz) * nn + zz * hv1;
        h1w[bb * 1024 + j] = h2;
        A.enc[(size_t)(p - 1) * (BB * HD) + bb * 1024 + j] = h2;
      }
    }
    grid.sync();
  }
}

// ===========================================================================
// Decoder kernels (unchanged from rounds 5/7/8, which passed)
// ===========================================================================
enum { G_ENC0 = 0, G_GRU = 1, G_SCR = 2, G_SCRGATE = 3, G_RELU = 4 };

struct Role {
  const float* srcA; const float* srcB;
  const float* Wa;   const float* Wb;
  const float* bih;  const float* bhh;
  const float* hv;   const float* scr;
  float* out; float* out2; float* scrw;
  int strA, strB, wstrA, K, gate, rowsLinear, gatherA, nsA, nsB;
};

__global__ __launch_bounds__(256) void fused_gemm(
    Role r0, Role r1, int split, int skipRole, int p,
    const float* __restrict__ x, const float* __restrict__ Wih0,
    const float* __restrict__ emb, const int* __restrict__ tok)
{
  __shared__ __align__(16) float Sk[64][SSTR];
  __shared__ __align__(16) float Wt[12][WSTR];
  __shared__ __align__(16) float part[4][16][4][4][4];

  const int blk = blockIdx.x;
  const int roleId = split ? (blk & 1) : 0;
  if (roleId == skipRole) return;
  const Role& R = roleId ? r1 : r0;
  const int bi2 = split ? (blk >> 1) : blk;
  const int j0 = bi2 * (R.rowsLinear ? 12 : 4);

  const int tid = threadIdx.x;
  const int tx = tid & 3;
  const int ty = (tid >> 2) & 15;
  const int kh = tid >> 6;

  float aR[4] = {0,0,0,0}, aZ[4] = {0,0,0,0}, aN2[4] = {0,0,0,0}, aN3[4] = {0,0,0,0};

  const int nit = R.K >> 6;

  for (int it = 0; it < nit; ++it) {
    const int kw = it << 6;
    const bool second = (R.srcB != nullptr) && (kw >= 1024);
    const int kloc = second ? (kw - 1024) : kw;

    float4 sv[4];
#pragma unroll
    for (int u = 0; u < 4; ++u) {
      int e = tid + (u << 8);
      int bq = e >> 4, f4 = e & 15;
      int bc = bq < BB ? bq : BB - 1;
      const float* rp;
      if (second)         rp = R.srcB + (size_t)bc * R.strB + kloc;
      else if (R.gatherA) rp = emb + (size_t)tok[bc] * HD + kw;
      else                rp = R.srcA + (size_t)bc * R.strA + kw;
      sv[u] = *(const float4*)(rp + (f4 << 2));
    }
    float4 wvq = make_float4(0.f, 0.f, 0.f, 0.f);
    if (tid < 192) {
      int r = tid >> 4, f4 = tid & 15;
      int wrow;
      if (R.rowsLinear) { int j = j0 + r; wrow = j < 1024 ? j : 1023; }
      else { int g = r >> 2, jj = r & 3; int j = j0 + jj; if (j > 1023) j = 1023;
             wrow = g * 1024 + j; }
      const float* wp = second ? (R.Wb + (size_t)wrow * 1024 + kloc)
                               : (R.Wa + (size_t)wrow * R.wstrA + kw);
      wvq = *(const float4*)(wp + (f4 << 2));
    }

    __syncthreads();
#pragma unroll
    for (int u = 0; u < 4; ++u) {
      int e = tid + (u << 8);
      int bq = e >> 4, f4 = e & 15;
      int k = f4 << 2;
      Sk[k + 0][bq] = sv[u].x;
      Sk[k + 1][bq] = sv[u].y;
      Sk[k + 2][bq] = sv[u].z;
      Sk[k + 3][bq] = sv[u].w;
    }
    if (tid < 192) {
      int r = tid >> 4, f4 = tid & 15;
      *(float4*)&Wt[r][f4 << 2] = wvq;
    }
    __syncthreads();

    const bool ns2 = second ? (R.nsB == 2) : (R.nsA == 2);
#define FMA4(A, wc, s) { A[0] = fmaf(wc, s.x, A[0]); A[1] = fmaf(wc, s.y, A[1]); \
                         A[2] = fmaf(wc, s.z, A[2]); A[3] = fmaf(wc, s.w, A[3]); }
#define CBLOCK(AN) \
    _Pragma("unroll") \
    for (int k4 = 0; k4 < 4; ++k4) { \
      const int kk = (kh << 4) + (k4 << 2); \
      float4 w0 = *(const float4*)&Wt[tx][kk]; \
      float4 w1 = *(const float4*)&Wt[4 + tx][kk]; \
      float4 w2 = *(const float4*)&Wt[8 + tx][kk]; \
      float4 s0 = *(const float4*)&Sk[kk + 0][ty << 2]; \
      float4 s1 = *(const float4*)&Sk[kk + 1][ty << 2]; \
      float4 s2 = *(const float4*)&Sk[kk + 2][ty << 2]; \
      float4 s3 = *(const float4*)&Sk[kk + 3][ty << 2]; \
      FMA4(aR, w0.x, s0) FMA4(aR, w0.y, s1) FMA4(aR, w0.z, s2) FMA4(aR, w0.w, s3) \
      FMA4(aZ, w1.x, s0) FMA4(aZ, w1.y, s1) FMA4(aZ, w1.z, s2) FMA4(aZ, w1.w, s3) \
      FMA4(AN, w2.x, s0) FMA4(AN, w2.y, s1) FMA4(AN, w2.z, s2) FMA4(AN, w2.w, s3) \
    }
    if (ns2) { CBLOCK(aN2) } else { CBLOCK(aN3) }
    __syncthreads();
  }

  *(float4*)&part[kh][ty][tx][0][0] = make_float4(aR[0], aR[1], aR[2], aR[3]);
  *(float4*)&part[kh][ty][tx][1][0] = make_float4(aZ[0], aZ[1], aZ[2], aZ[3]);
  *(float4*)&part[kh][ty][tx][2][0] = make_float4(aN2[0], aN2[1], aN2[2], aN2[3]);
  *(float4*)&part[kh][ty][tx][3][0] = make_float4(aN3[0], aN3[1], aN3[2], aN3[3]);
  __syncthreads();

  if (tid < 200) {
    int bq = tid >> 2, jj = tid & 3;
    int py = bq >> 2, pi = bq & 3;
    float d0 = 0.f, d1 = 0.f, d2 = 0.f, d3 = 0.f;
#pragma unroll
    for (int q = 0; q < 4; ++q) {
      d0 += part[q][py][jj][0][pi];
      d1 += part[q][py][jj][1][pi];
      d2 += part[q][py][jj][2][pi];
      d3 += part[q][py][jj][3][pi];
    }
    if (R.gate == G_ENC0) {
      int j = j0 + jj;
      float x0 = x[bq * 914 + p], x1 = x[bq * 914 + 457 + p], pf = (float)p;
      const float* w3r = Wih0 + (size_t)j * 3;
      const float* w3z = Wih0 + (size_t)(1024 + j) * 3;
      const float* w3n = Wih0 + (size_t)(2048 + j) * 3;
      float gir = w3r[0]*x0 + w3r[1]*x1 + w3r[2]*pf + R.bih[j];
      float giz = w3z[0]*x0 + w3z[1]*x1 + w3z[2]*pf + R.bih[1024 + j];
      float gin = w3n[0]*x0 + w3n[1]*x1 + w3n[2]*pf + R.bih[2048 + j];
      float rr = SIGM(gir + d0 + R.bhh[j]);
      float zz = SIGM(giz + d1 + R.bhh[1024 + j]);
      float nn = tanhf(gin + rr * (d3 + R.bhh[2048 + j]));
      float hv = R.hv[bq * 1024 + j];
      R.out[bq * 1024 + j] = (1.f - zz) * nn + zz * hv;
    } else if (R.gate == G_GRU) {
      int j = j0 + jj;
      float rr = SIGM(d0 + R.bih[j] + R.bhh[j]);
      float zz = SIGM(d1 + R.bih[1024 + j] + R.bhh[1024 + j]);
      float nn = tanhf(d2 + R.bih[2048 + j] + rr * (d3 + R.bhh[2048 + j]));
      float hv = R.hv[bq * 1024 + j];
      float h2 = (1.f - zz) * nn + zz * hv;
      R.out[bq * 1024 + j] = h2;
      if (R.out2) R.out2[bq * 1024 + j] = h2;
    } else if (R.gate == G_SCR) {
      int j = j0 + jj;
      R.scrw[(size_t)j * 64 + bq] = d0;
      R.scrw[(size_t)(1024 + j) * 64 + bq] = d1;
      R.scrw[(size_t)(2048 + j) * 64 + bq] = d3;
    } else if (R.gate == G_SCRGATE) {
      int j = j0 + jj;
      float ghr = R.scr[(size_t)j * 64 + bq] + R.bhh[j];
      float ghz = R.scr[(size_t)(1024 + j) * 64 + bq] + R.bhh[1024 + j];
      float ghn = R.scr[(size_t)(2048 + j) * 64 + bq] + R.bhh[2048 + j];
      float rr = SIGM(d0 + R.bih[j] + ghr);
      float zz = SIGM(d1 + R.bih[1024 + j] + ghz);
      float nn = tanhf(d2 + R.bih[2048 + j] + rr * ghn);
      float hv = R.hv[bq * 1024 + j];
      float h2 = (1.f - zz) * nn + zz * hv;
      R.out[bq * 1024 + j] = h2;
      R.out2[bq * 2048 + j] = h2;
    } else {
#pragma unroll
      for (int g = 0; g < 3; ++g) {
        int j = j0 + g * 4 + jj;
        float dg = (g == 0) ? d0 : ((g == 1) ? d1 : d2);
        if (j < 1024) R.out[bq * 1024 + j] = fmaxf(dg + R.bih[j], 0.f);
      }
    }
  }
}

__global__ __launch_bounds__(256) void score_kernel(
    const float* __restrict__ enc, const float* __restrict__ comb,
    float* __restrict__ sc)
{
  int gw = (blockIdx.x * 256 + threadIdx.x) >> 6;
  int lane = threadIdx.x & 63;
  if (gw >= BB * SS) return;
  int b = gw / SS, s = gw - b * SS;
  const float* e = enc + ((size_t)s * BB + b) * HD;
  const float* q = comb + (size_t)b * 2048;
  float a = 0.f;
#pragma unroll
  for (int i = 0; i < 16; i++) a += e[lane + 64 * i] * q[lane + 64 * i];
  for (int off = 32; off; off >>= 1) a += __shfl_down(a, off);
  if (!lane) sc[b * SS + s] = a;
}

__global__ __launch_bounds__(256) void softmax_amix_kernel(
    const float* __restrict__ sc, const float* __restrict__ enc,
    float* __restrict__ comb, float* __restrict__ attn_out, int t)
{
  __shared__ float w[SS];
  __shared__ float red[256];
  int blk = blockIdx.x; int b = blk / 5, sl = blk - b * 5;
  int tid = threadIdx.x;
  float m = -1e30f;
  for (int s = tid; s < SS; s += 256) { float v = sc[b * SS + s]; w[s] = v; m = fmaxf(m, v); }
  red[tid] = m; __syncthreads();
  for (int o = 128; o; o >>= 1) { if (tid < o) red[tid] = fmaxf(red[tid], red[tid + o]); __syncthreads(); }
  m = red[0]; __syncthreads();
  float sum = 0.f;
  for (int s = tid; s < SS; s += 256) { float e = expf(w[s] - m); w[s] = e; sum += e; }
  red[tid] = sum; __syncthreads();
  for (int o = 128; o; o >>= 1) { if (tid < o) red[tid] += red[tid + o]; __syncthreads(); }
  float inv = 1.f / red[0];
  __syncthreads();
  for (int s = tid; s < SS; s += 256) w[s] *= inv;
  __syncthreads();
  if (sl == 0)
    for (int s = tid; s < SS; s += 256) attn_out[((size_t)b * SS + s) * TT + t] = w[s];
  int j0 = sl * 208; int jl = min(208, 1024 - j0);
  if (tid < jl) {
    int j = j0 + tid; float a = 0.f;
#pragma unroll 4
    for (int s = 0; s < SS; s++) a += w[s] * enc[((size_t)s * BB + b) * HD + j];
    comb[(size_t)b * 2048 + HD + j] = a;
  }
}

__global__ __launch_bounds__(256) void logits_argmax_kernel(
    const float* __restrict__ hfc, const float* __restrict__ fcW,
    const float* __restrict__ fcb, float* __restrict__ outv, int t,
    int* __restrict__ tok)
{
  __shared__ float lg[32];
  int b = blockIdx.x, tid = threadIdx.x;
  int wvv = tid >> 6, lane = tid & 63;
  const float* hb = hfc + (size_t)b * HD;
  for (int v = wvv; v < VV; v += 4) {
    const float* wr = fcW + (size_t)v * HD;
    float a = 0.f;
#pragma unroll
    for (int i = 0; i < 16; i++) a += hb[lane + 64 * i] * wr[lane + 64 * i];
    for (int off = 32; off; off >>= 1) a += __shfl_down(a, off);
    if (!lane) lg[v] = a + fcb[v];
  }
  __syncthreads();
  if (tid == 0) {
    float best = lg[0]; int bi = 0;
    for (int v = 1; v < VV; v++) { if (lg[v] > best) { best = lg[v]; bi = v; } }
    tok[b] = bi;
  }
  if (tid < VV) outv[((size_t)b * TT + t) * VV + tid] = lg[tid];
}

__global__ __launch_bounds__(256) void init_kernel(float* __restrict__ hbufs,
                                                   int* __restrict__ tok)
{
  int i = blockIdx.x * 256 + threadIdx.x;
  if (i < 204800) hbufs[i] = 0.f;
  if (i < BB) tok[i] = 0;
}

__global__ __launch_bounds__(256) void hidcopy_kernel(
    const float* __restrict__ h0, const float* __restrict__ h1,
    float* __restrict__ outh)
{
  int i = blockIdx.x * 256 + threadIdx.x;
  if (i < 51200) { outh[i] = h0[i]; outh[51200 + i] = h1[i]; }
}

// ---------------------------------------------------------------------------
extern "C" void kernel_launch(void* const* d_in, const int* in_sizes, int n_in,
                              void* d_out, int out_size, void* d_ws, size_t ws_size,
                              hipStream_t stream)
{
  const float* x     = (const float*)d_in[0];
  const float* emb   = (const float*)d_in[1];
  const float* eWih0 = (const float*)d_in[2];
  const float* eWhh0 = (const float*)d_in[3];
  const float* ebih0 = (const float*)d_in[4];
  const float* ebhh0 = (const float*)d_in[5];
  const float* eWih1 = (const float*)d_in[6];
  const float* eWhh1 = (const float*)d_in[7];
  const float* ebih1 = (const float*)d_in[8];
  const float* ebhh1 = (const float*)d_in[9];
  const float* dWih  = (const float*)d_in[10];
  const float* dWhh  = (const float*)d_in[11];
  const float* dbih  = (const float*)d_in[12];
  const float* dbhh  = (const float*)d_in[13];
  const float* attnW = (const float*)d_in[14];
  const float* attnB = (const float*)d_in[15];
  const float* fcW   = (const float*)d_in[16];
  const float* fcB   = (const float*)d_in[17];
  float* out = (float*)d_out;

  float* ws = (float*)d_ws;
  float* h0b[2] = { ws,          ws + 51200 };
  float* h1b[2] = { ws + 102400, ws + 153600 };
  float* enc    = ws + 204800;
  float* scr    = enc + (size_t)SS * BB * HD;
  float* comb   = scr + 3072 * 64;
  float* scoreb = comb + BB * 2048;
  float* hfc    = scoreb + BB * SS;
  int*   tok    = (int*)(hfc + BB * HD);

  float* out_vec  = out;
  float* out_hid  = out + BB * TT * VV;
  float* out_attn = out_hid + 2 * BB * HD;

  const float* dWih1 = dWih + (size_t)3072 * 1024;
  const float* dWhh1 = dWhh + (size_t)3072 * 1024;
  const float* dbih1 = dbih + 3072;
  const float* dbhh1 = dbhh + 3072;

  init_kernel<<<800, 256, 0, stream>>>(ws, tok);

  // ---- encoder: single persistent cooperative kernel ----
  EncArgs ea;
  ea.x = x; ea.Wih0 = eWih0; ea.Whh0 = eWhh0; ea.bih0 = ebih0; ea.bhh0 = ebhh0;
  ea.Wih1 = eWih1; ea.Whh1 = eWhh1; ea.bih1 = ebih1; ea.bhh1 = ebhh1;
  ea.h0a = h0b[0]; ea.h0b2 = h0b[1]; ea.h1a = h1b[0]; ea.h1b2 = h1b[1];
  ea.enc = enc;
  void* kargs[] = { (void*)&ea };
  hipLaunchCooperativeKernel((void*)enc_persistent, dim3(256), dim3(1024),
                             kargs, 0, stream);

  Role Z{};

  // ---- decoder (unchanged round-5 structure) ----
  for (int t = 0; t < TT; ++t) {
    float* h0r = h0b[t & 1]; float* h0w = h0b[(t + 1) & 1];
    float* h1r = h1b[t & 1]; float* h1w = h1b[(t + 1) & 1];

    Role DL0 = Z;
    DL0.gatherA = 1; DL0.srcB = h0r; DL0.strB = 1024;
    DL0.Wa = dWih; DL0.wstrA = 1024; DL0.Wb = dWhh;
    DL0.bih = dbih; DL0.bhh = dbhh; DL0.hv = h0r; DL0.out = h0w;
    DL0.K = 2048; DL0.gate = G_GRU; DL0.nsA = 2; DL0.nsB = 3;

    Role GH1 = Z;
    GH1.srcA = h1r; GH1.strA = 1024; GH1.Wa = dWhh1; GH1.wstrA = 1024;
    GH1.scrw = scr; GH1.K = 1024; GH1.gate = G_SCR; GH1.nsA = 3; GH1.nsB = 3;

    fused_gemm<<<512, 256, 0, stream>>>(DL0, GH1, 1, -1, t, x, eWih0, emb, tok);

    Role GI1 = Z;
    GI1.srcA = h0w; GI1.strA = 1024; GI1.Wa = dWih1; GI1.wstrA = 1024;
    GI1.bih = dbih1; GI1.bhh = dbhh1; GI1.hv = h1r; GI1.scr = scr;
    GI1.out = h1w; GI1.out2 = comb;
    GI1.K = 1024; GI1.gate = G_SCRGATE; GI1.nsA = 2; GI1.nsB = 2;

    fused_gemm<<<256, 256, 0, stream>>>(GI1, Z, 0, -1, t, x, eWih0, emb, tok);

    score_kernel<<<(BB * SS * 64 + 255) / 256, 256, 0, stream>>>(enc, comb, scoreb);
    softmax_amix_kernel<<<250, 256, 0, stream>>>(scoreb, enc, comb, out_attn, t);

    Role AF = Z;
    AF.srcA = comb; AF.strA = 2048; AF.Wa = attnW; AF.wstrA = 2048;
    AF.bih = attnB; AF.out = hfc;
    AF.K = 2048; AF.gate = G_RELU; AF.rowsLinear = 1; AF.nsA = 2; AF.nsB = 2;

    fused_gemm<<<86, 256, 0, stream>>>(AF, Z, 0, -1, t, x, eWih0, emb, tok);

    logits_argmax_kernel<<<BB, 256, 0, stream>>>(hfc, fcW, fcB, out_vec, t, tok);
  }

  hidcopy_kernel<<<200, 256, 0, stream>>>(h0b[0], h1b[0], out_hid);
}